// Round 1
// baseline (2962.864 us; speedup 1.0000x reference)
//
#include <hip/hip_runtime.h>

#define NN 50000
#define EE 640000
#define DD 128
#define KPRE 320
#define KPOST 1664
#define AVGD 3.5f
#define EPSF 1e-5f

typedef unsigned int u32;
typedef unsigned short u16;

__device__ __forceinline__ u16 f2bf(float f) {
    u32 u = __float_as_uint(f);
    u32 r = (u + 0x7fffu + ((u >> 16) & 1u)) >> 16;
    return (u16)r;
}
__device__ __forceinline__ float bf2f(u16 b) {
    return __uint_as_float(((u32)b) << 16);
}
__device__ __forceinline__ u32 pack2(float a, float b) {
    return (u32)f2bf(a) | ((u32)f2bf(b) << 16);
}

// ---------------- CSR construction (once per launch) ----------------

__global__ void deg_kernel(const int* __restrict__ dst, int* __restrict__ deg) {
    int i = blockIdx.x * blockDim.x + threadIdx.x;
    if (i < EE) atomicAdd(&deg[dst[i]], 1);
}

__global__ void scaler_kernel(const int* __restrict__ deg,
                              float* __restrict__ amp, float* __restrict__ att) {
    int i = blockIdx.x * blockDim.x + threadIdx.x;
    if (i < NN) {
        float d = (float)deg[i];
        float logd = logf(d + 1.0f);
        amp[i] = logd / AVGD;
        att[i] = AVGD / fmaxf(logd, EPSF);
    }
}

// single-block exclusive scan: rowstart[0]=0, rowstart[i+1]=sum(deg[0..i])
__global__ void scan_kernel(const int* __restrict__ deg, int* __restrict__ rowstart) {
    __shared__ int wsum[16];
    int lane = threadIdx.x & 63;
    int wid = threadIdx.x >> 6;
    int carry = 0;
    if (threadIdx.x == 0) rowstart[0] = 0;
    for (int base = 0; base < NN; base += 1024) {
        int i = base + threadIdx.x;
        int v = (i < NN) ? deg[i] : 0;
        int x = v;
#pragma unroll
        for (int off = 1; off < 64; off <<= 1) {
            int y = __shfl_up(x, off, 64);
            if (lane >= off) x += y;
        }
        if (lane == 63) wsum[wid] = x;
        __syncthreads();
        if (wid == 0 && lane < 16) {
            int w = wsum[lane];
#pragma unroll
            for (int off = 1; off < 16; off <<= 1) {
                int y = __shfl_up(w, off, 64);
                if (lane >= off) w += y;
            }
            wsum[lane] = w;
        }
        __syncthreads();
        int wofs = (wid > 0) ? wsum[wid - 1] : 0;
        int total = wsum[15];
        if (i < NN) rowstart[i + 1] = carry + wofs + x;
        carry += total;
        __syncthreads();
    }
}

__global__ void fill_kernel(const int* __restrict__ dst, const int* __restrict__ rowstart,
                            int* __restrict__ cursor, int* __restrict__ eid) {
    int i = blockIdx.x * blockDim.x + threadIdx.x;
    if (i < EE) {
        int d = dst[i];
        int pos = rowstart[d] + atomicAdd(&cursor[d], 1);
        eid[pos] = i;
    }
}

// ---------------- Pretrans GEMM: m[E,128] = cat(h[src],h[dst],e) @ W + b ----------------
// tile: 64 edges x 128 cols, BK=16, 256 threads, 4x8 micro-tile per thread

__global__ __launch_bounds__(256) void pretrans_kernel(
    const float* __restrict__ h, const float* __restrict__ efeat,
    const int* __restrict__ src, const int* __restrict__ dst,
    const float* __restrict__ W, const float* __restrict__ bias,
    u16* __restrict__ m) {
    __shared__ float As[16][68];   // [kk][row], pad stride 68 keeps float4 alignment
    __shared__ float Bs[16][132];  // [kk][col]
    int t = threadIdx.x;
    int row = t & 63;
    int kslot = t >> 6;
    int r0 = (t >> 4) << 2;
    int c0 = (t & 15) << 3;
    int gr = blockIdx.x * 64 + row;  // EE % 64 == 0, no guard
    int sIdx = src[gr];
    int dIdx = dst[gr];
    float acc[4][8];
#pragma unroll
    for (int i = 0; i < 4; i++)
#pragma unroll
        for (int j = 0; j < 8; j++) acc[i][j] = 0.f;

    for (int k0 = 0; k0 < KPRE; k0 += 16) {
#pragma unroll
        for (int i = 0; i < 4; i++) {
            int kk = kslot + 4 * i;
            int k = k0 + kk;
            float v;
            if (k0 < 128)       v = h[(size_t)sIdx * 128 + k];
            else if (k0 < 256)  v = h[(size_t)dIdx * 128 + (k - 128)];
            else                v = efeat[(size_t)gr * 64 + (k - 256)];
            As[kk][row] = v;
        }
#pragma unroll
        for (int i = 0; i < 2; i++) {
            int f = t + i * 256;
            int kk = f >> 5;
            int c4 = (f & 31) << 2;
            *(float4*)&Bs[kk][c4] = *(const float4*)&W[(size_t)(k0 + kk) * 128 + c4];
        }
        __syncthreads();
#pragma unroll
        for (int kk = 0; kk < 16; kk++) {
            float4 a = *(const float4*)&As[kk][r0];
            float4 b0 = *(const float4*)&Bs[kk][c0];
            float4 b1 = *(const float4*)&Bs[kk][c0 + 4];
            float av[4] = {a.x, a.y, a.z, a.w};
            float bv[8] = {b0.x, b0.y, b0.z, b0.w, b1.x, b1.y, b1.z, b1.w};
#pragma unroll
            for (int i2 = 0; i2 < 4; i2++)
#pragma unroll
                for (int j = 0; j < 8; j++) acc[i2][j] += av[i2] * bv[j];
        }
        __syncthreads();
    }
#pragma unroll
    for (int i = 0; i < 4; i++) {
        size_t ge = (size_t)blockIdx.x * 64 + r0 + i;
        u32 w0 = pack2(acc[i][0] + bias[c0 + 0], acc[i][1] + bias[c0 + 1]);
        u32 w1 = pack2(acc[i][2] + bias[c0 + 2], acc[i][3] + bias[c0 + 3]);
        u32 w2 = pack2(acc[i][4] + bias[c0 + 4], acc[i][5] + bias[c0 + 5]);
        u32 w3 = pack2(acc[i][6] + bias[c0 + 6], acc[i][7] + bias[c0 + 7]);
        uint4 pk; pk.x = w0; pk.y = w1; pk.z = w2; pk.w = w3;
        *(uint4*)&m[ge * 128 + c0] = pk;
    }
}

// ---------------- Aggregation: one wave per node, CSR walk ----------------
// agg layout per node: [mean(128) | max(128) | min(128) | std(128)], fp32

__global__ __launch_bounds__(256) void agg_kernel(
    const u16* __restrict__ m, const int* __restrict__ rowstart,
    const int* __restrict__ eid, float* __restrict__ agg) {
    int w = blockIdx.x * 4 + (threadIdx.x >> 6);
    if (w >= NN) return;
    int lane = threadIdx.x & 63;
    int beg = rowstart[w], end = rowstart[w + 1];
    float s0 = 0.f, s1 = 0.f, q0 = 0.f, q1 = 0.f;
    float mx0 = -3.402823e38f, mx1 = -3.402823e38f;
    float mn0 = 3.402823e38f, mn1 = 3.402823e38f;
    for (int p = beg; p < end; p++) {
        int e2 = eid[p];
        u32 pk = *(const u32*)&m[(size_t)e2 * 128 + 2 * lane];
        float v0 = bf2f((u16)(pk & 0xffffu));
        float v1 = bf2f((u16)(pk >> 16));
        s0 += v0; s1 += v1;
        q0 += v0 * v0; q1 += v1 * v1;
        mx0 = fmaxf(mx0, v0); mx1 = fmaxf(mx1, v1);
        mn0 = fminf(mn0, v0); mn1 = fminf(mn1, v1);
    }
    size_t base = (size_t)w * 512 + 2 * lane;
    int d = end - beg;
    if (d > 0) {
        float inv = 1.0f / (float)d;
        float me0 = s0 * inv, me1 = s1 * inv;
        float var0 = fmaxf(q0 * inv - me0 * me0, 0.f);
        float var1 = fmaxf(q1 * inv - me1 * me1, 0.f);
        *(float2*)&agg[base + 0]   = make_float2(me0, me1);
        *(float2*)&agg[base + 128] = make_float2(mx0, mx1);
        *(float2*)&agg[base + 256] = make_float2(mn0, mn1);
        *(float2*)&agg[base + 384] = make_float2(sqrtf(var0 + EPSF), sqrtf(var1 + EPSF));
    } else {
        *(float2*)&agg[base + 0]   = make_float2(0.f, 0.f);
        *(float2*)&agg[base + 128] = make_float2(0.f, 0.f);
        *(float2*)&agg[base + 256] = make_float2(0.f, 0.f);
        *(float2*)&agg[base + 384] = make_float2(0.f, 0.f);
    }
}

// ---------------- Post GEMM: ht[N,128] = cat(h, agg, agg*amp, agg*att) @ W + b ----------------

__global__ __launch_bounds__(256) void post_kernel(
    const float* __restrict__ h, const float* __restrict__ agg,
    const float* __restrict__ amp, const float* __restrict__ att,
    const float* __restrict__ W, const float* __restrict__ bias,
    float* __restrict__ ht) {
    __shared__ float As[16][68];
    __shared__ float Bs[16][132];
    int t = threadIdx.x;
    int row = t & 63;
    int kslot = t >> 6;
    int r0 = (t >> 4) << 2;
    int c0 = (t & 15) << 3;
    int gnode = blockIdx.x * 64 + row;
    int node = gnode < NN ? gnode : NN - 1;
    float ampv = amp[node], attv = att[node];
    float acc[4][8];
#pragma unroll
    for (int i = 0; i < 4; i++)
#pragma unroll
        for (int j = 0; j < 8; j++) acc[i][j] = 0.f;

    for (int k0 = 0; k0 < KPOST; k0 += 16) {
#pragma unroll
        for (int i = 0; i < 4; i++) {
            int kk = kslot + 4 * i;
            int k = k0 + kk;
            float v;
            if (k0 < 128)        v = h[(size_t)node * 128 + k];
            else if (k0 < 640)   v = agg[(size_t)node * 512 + (k - 128)];
            else if (k0 < 1152)  v = agg[(size_t)node * 512 + (k - 640)] * ampv;
            else                 v = agg[(size_t)node * 512 + (k - 1152)] * attv;
            As[kk][row] = v;
        }
#pragma unroll
        for (int i = 0; i < 2; i++) {
            int f = t + i * 256;
            int kk = f >> 5;
            int c4 = (f & 31) << 2;
            *(float4*)&Bs[kk][c4] = *(const float4*)&W[(size_t)(k0 + kk) * 128 + c4];
        }
        __syncthreads();
#pragma unroll
        for (int kk = 0; kk < 16; kk++) {
            float4 a = *(const float4*)&As[kk][r0];
            float4 b0 = *(const float4*)&Bs[kk][c0];
            float4 b1 = *(const float4*)&Bs[kk][c0 + 4];
            float av[4] = {a.x, a.y, a.z, a.w};
            float bv[8] = {b0.x, b0.y, b0.z, b0.w, b1.x, b1.y, b1.z, b1.w};
#pragma unroll
            for (int i2 = 0; i2 < 4; i2++)
#pragma unroll
                for (int j = 0; j < 8; j++) acc[i2][j] += av[i2] * bv[j];
        }
        __syncthreads();
    }
#pragma unroll
    for (int i = 0; i < 4; i++) {
        int grow = blockIdx.x * 64 + r0 + i;
        if (grow < NN) {
#pragma unroll
            for (int j = 0; j < 8; j++)
                ht[(size_t)grow * 128 + c0 + j] = acc[i][j] + bias[c0 + j];
        }
    }
}

// ---------------- Mix GEMM + leaky_relu + residual (in-place h update) ----------------

__global__ __launch_bounds__(256) void mix_kernel(
    const float* __restrict__ ht, const float* __restrict__ W,
    const float* __restrict__ bias, float* __restrict__ h) {
    __shared__ float As[16][68];
    __shared__ float Bs[16][132];
    int t = threadIdx.x;
    int row = t & 63;
    int kslot = t >> 6;
    int r0 = (t >> 4) << 2;
    int c0 = (t & 15) << 3;
    int gnode = blockIdx.x * 64 + row;
    int node = gnode < NN ? gnode : NN - 1;
    float acc[4][8];
#pragma unroll
    for (int i = 0; i < 4; i++)
#pragma unroll
        for (int j = 0; j < 8; j++) acc[i][j] = 0.f;

    for (int k0 = 0; k0 < 128; k0 += 16) {
#pragma unroll
        for (int i = 0; i < 4; i++) {
            int kk = kslot + 4 * i;
            int k = k0 + kk;
            As[kk][row] = ht[(size_t)node * 128 + k];
        }
#pragma unroll
        for (int i = 0; i < 2; i++) {
            int f = t + i * 256;
            int kk = f >> 5;
            int c4 = (f & 31) << 2;
            *(float4*)&Bs[kk][c4] = *(const float4*)&W[(size_t)(k0 + kk) * 128 + c4];
        }
        __syncthreads();
#pragma unroll
        for (int kk = 0; kk < 16; kk++) {
            float4 a = *(const float4*)&As[kk][r0];
            float4 b0 = *(const float4*)&Bs[kk][c0];
            float4 b1 = *(const float4*)&Bs[kk][c0 + 4];
            float av[4] = {a.x, a.y, a.z, a.w};
            float bv[8] = {b0.x, b0.y, b0.z, b0.w, b1.x, b1.y, b1.z, b1.w};
#pragma unroll
            for (int i2 = 0; i2 < 4; i2++)
#pragma unroll
                for (int j = 0; j < 8; j++) acc[i2][j] += av[i2] * bv[j];
        }
        __syncthreads();
    }
#pragma unroll
    for (int i = 0; i < 4; i++) {
        int grow = blockIdx.x * 64 + r0 + i;
        if (grow < NN) {
#pragma unroll
            for (int j = 0; j < 8; j++) {
                float val = acc[i][j] + bias[c0 + j];
                val = val > 0.f ? val : 0.01f * val;
                size_t idx = (size_t)grow * 128 + c0 + j;
                h[idx] = h[idx] + val;
            }
        }
    }
}

// ---------------- launch ----------------

extern "C" void kernel_launch(void* const* d_in, const int* in_sizes, int n_in,
                              void* d_out, int out_size, void* d_ws, size_t ws_size,
                              hipStream_t stream) {
    (void)in_sizes; (void)n_in; (void)out_size; (void)ws_size;
    const float* h0    = (const float*)d_in[0];
    const float* efeat = (const float*)d_in[1];
    const int* src     = (const int*)d_in[2];
    const int* dst     = (const int*)d_in[3];
    const float* preW  = (const float*)d_in[4];
    const float* preB  = (const float*)d_in[5];
    const float* postW = (const float*)d_in[6];
    const float* postB = (const float*)d_in[7];
    const float* mixW  = (const float*)d_in[8];
    const float* mixB  = (const float*)d_in[9];
    float* hcur = (float*)d_out;

    char* ws = (char*)d_ws;
    size_t off = 0;
    auto alloc = [&](size_t bytes) {
        void* p = ws + off;
        off += (bytes + 255) & ~(size_t)255;
        return p;
    };
    u16* mbuf      = (u16*)alloc((size_t)EE * 128 * 2);   // 163.84 MB
    float* agg     = (float*)alloc((size_t)NN * 512 * 4); // 102.40 MB
    int* eid       = (int*)alloc((size_t)EE * 4);
    int* deg       = (int*)alloc((size_t)NN * 4);
    int* rowstart  = (int*)alloc((size_t)(NN + 1) * 4);
    int* cursor    = (int*)alloc((size_t)NN * 4);
    float* amp     = (float*)alloc((size_t)NN * 4);
    float* att     = (float*)alloc((size_t)NN * 4);
    float* ht      = (float*)mbuf;  // alias: m dead once agg built, mix done before next pretrans

    hipMemsetAsync(deg, 0, (size_t)NN * 4, stream);
    hipMemsetAsync(cursor, 0, (size_t)NN * 4, stream);
    hipMemcpyAsync(hcur, h0, (size_t)NN * 128 * 4, hipMemcpyDeviceToDevice, stream);

    deg_kernel<<<(EE + 255) / 256, 256, 0, stream>>>(dst, deg);
    scaler_kernel<<<(NN + 255) / 256, 256, 0, stream>>>(deg, amp, att);
    scan_kernel<<<1, 1024, 0, stream>>>(deg, rowstart);
    fill_kernel<<<(EE + 255) / 256, 256, 0, stream>>>(dst, rowstart, cursor, eid);

    for (int l = 0; l < 2; l++) {
        pretrans_kernel<<<EE / 64, 256, 0, stream>>>(
            hcur, efeat, src, dst,
            preW + (size_t)l * KPRE * 128, preB + (size_t)l * 128, mbuf);
        agg_kernel<<<(NN + 3) / 4, 256, 0, stream>>>(mbuf, rowstart, eid, agg);
        post_kernel<<<(NN + 63) / 64, 256, 0, stream>>>(
            hcur, agg, amp, att,
            postW + (size_t)l * KPOST * 128, postB + (size_t)l * 128, ht);
        mix_kernel<<<(NN + 63) / 64, 256, 0, stream>>>(
            ht, mixW + (size_t)l * 128 * 128, mixB + (size_t)l * 128, hcur);
    }
}

// Round 3
// 1374.848 us; speedup vs baseline: 2.1550x; 2.1550x over previous
//
#include <hip/hip_runtime.h>

#define NN 50000
#define EE 640000
#define DD 128
#define AVGD 3.5f
#define EPSF 1e-5f

typedef unsigned int u32;
typedef unsigned short u16;
typedef __attribute__((ext_vector_type(8))) short short8v;  // 8 bf16 in 4 VGPRs
typedef __attribute__((ext_vector_type(4))) float f32x4;

__device__ __forceinline__ u16 f2bf(float f) {
    u32 u = __float_as_uint(f);
    u32 r = (u + 0x7fffu + ((u >> 16) & 1u)) >> 16;
    return (u16)r;
}
__device__ __forceinline__ float bf2f(u16 b) {
    return __uint_as_float(((u32)b) << 16);
}
__device__ __forceinline__ u32 pack2(float a, float b) {
    return (u32)f2bf(a) | ((u32)f2bf(b) << 16);
}

// ---------------- CSR construction ----------------

__global__ void deg_kernel(const int* __restrict__ dst, int* __restrict__ deg) {
    int i = blockIdx.x * blockDim.x + threadIdx.x;
    if (i < EE) atomicAdd(&deg[dst[i]], 1);
}

__global__ void scan_kernel(const int* __restrict__ deg, int* __restrict__ rowstart) {
    __shared__ int wsum[16];
    int lane = threadIdx.x & 63;
    int wid = threadIdx.x >> 6;
    int carry = 0;
    if (threadIdx.x == 0) rowstart[0] = 0;
    for (int base = 0; base < NN; base += 1024) {
        int i = base + threadIdx.x;
        int v = (i < NN) ? deg[i] : 0;
        int x = v;
#pragma unroll
        for (int off = 1; off < 64; off <<= 1) {
            int y = __shfl_up(x, off, 64);
            if (lane >= off) x += y;
        }
        if (lane == 63) wsum[wid] = x;
        __syncthreads();
        if (wid == 0 && lane < 16) {
            int w = wsum[lane];
#pragma unroll
            for (int off = 1; off < 16; off <<= 1) {
                int y = __shfl_up(w, off, 64);
                if (lane >= off) w += y;
            }
            wsum[lane] = w;
        }
        __syncthreads();
        int wofs = (wid > 0) ? wsum[wid - 1] : 0;
        int total = wsum[15];
        if (i < NN) rowstart[i + 1] = carry + wofs + x;
        carry += total;
        __syncthreads();
    }
}

__global__ void fill_kernel(const int* __restrict__ dst, const int* __restrict__ rowstart,
                            int* __restrict__ cursor, int* __restrict__ eid) {
    int i = blockIdx.x * blockDim.x + threadIdx.x;
    if (i < EE) {
        int d = dst[i];
        int pos = rowstart[d] + atomicAdd(&cursor[d], 1);
        eid[pos] = i;
    }
}

// ---------------- converts ----------------

// h fp32 -> bf16, 4 elems/thread
__global__ void cvt_h_kernel(const float* __restrict__ h, u16* __restrict__ hb) {
    int i = (blockIdx.x * blockDim.x + threadIdx.x) * 4;
    float4 v = *(const float4*)&h[i];
    uint2 p;
    p.x = pack2(v.x, v.y);
    p.y = pack2(v.z, v.w);
    *(uint2*)&hb[i] = p;
}

// W[K][128] fp32 -> Wt[128][K] bf16
__global__ void cvt_wt_kernel(const float* __restrict__ W, u16* __restrict__ Wt, int K) {
    int idx = blockIdx.x * blockDim.x + threadIdx.x;
    if (idx < 128 * K) {
        int c = idx / K;
        int k = idx - c * K;
        Wt[idx] = f2bf(W[(size_t)k * 128 + c]);
    }
}

// ---------------- Pretrans MFMA: m[E,128] = cat(h[src],h[dst],e) @ W + b ----------------
// Per wave: 64 edges x 128 cols, no LDS. Computes D = Wt_slice(A) * Z^T(B):
//   A-frag: lane reads Wt[(cs*16 + (l&15))][k0 + (l>>4)*8 .. +7]
//   B-frag: lane reads Z[edge(es*16 + (l&15))][k0 + (l>>4)*8 .. +7]  (the gather)
//   D: out_col = cs*16 + (l>>4)*4 + reg, edge = es*16 + (l&15)

__global__ __launch_bounds__(256, 2) void pretrans_mfma(
    const u16* __restrict__ hb, const float* __restrict__ efeat,
    const int* __restrict__ src, const int* __restrict__ dst,
    const u16* __restrict__ Wt, const float* __restrict__ bias,
    u16* __restrict__ m) {
    int lane = threadIdx.x & 63;
    int wid = threadIdx.x >> 6;
    int r = lane & 15;
    int g = lane >> 4;
    size_t ebase = (size_t)blockIdx.x * 256 + wid * 64;

    int eIdx[4];
    const u16* srow[4];
    const u16* drow[4];
#pragma unroll
    for (int es = 0; es < 4; es++) {
        int e2 = (int)ebase + es * 16 + r;
        eIdx[es] = e2;
        srow[es] = hb + (size_t)src[e2] * 128;
        drow[es] = hb + (size_t)dst[e2] * 128;
    }

    f32x4 acc[4][8];
#pragma unroll
    for (int es = 0; es < 4; es++)
#pragma unroll
        for (int cs = 0; cs < 8; cs++) acc[es][cs] = (f32x4)(0.f);

    // segment 1: k in [0,128) from h[src]
#pragma unroll
    for (int ks = 0; ks < 4; ks++) {
        int k0 = ks * 32;
        short8v b0 = *(const short8v*)(srow[0] + k0 + g * 8);
        short8v b1 = *(const short8v*)(srow[1] + k0 + g * 8);
        short8v b2 = *(const short8v*)(srow[2] + k0 + g * 8);
        short8v b3 = *(const short8v*)(srow[3] + k0 + g * 8);
#pragma unroll
        for (int cs = 0; cs < 8; cs++) {
            short8v a = *(const short8v*)(Wt + (size_t)(cs * 16 + r) * 320 + k0 + g * 8);
            acc[0][cs] = __builtin_amdgcn_mfma_f32_16x16x32_bf16(a, b0, acc[0][cs], 0, 0, 0);
            acc[1][cs] = __builtin_amdgcn_mfma_f32_16x16x32_bf16(a, b1, acc[1][cs], 0, 0, 0);
            acc[2][cs] = __builtin_amdgcn_mfma_f32_16x16x32_bf16(a, b2, acc[2][cs], 0, 0, 0);
            acc[3][cs] = __builtin_amdgcn_mfma_f32_16x16x32_bf16(a, b3, acc[3][cs], 0, 0, 0);
        }
    }
    // segment 2: k in [128,256) from h[dst]
#pragma unroll
    for (int ks = 0; ks < 4; ks++) {
        int k0 = ks * 32;
        short8v b0 = *(const short8v*)(drow[0] + k0 + g * 8);
        short8v b1 = *(const short8v*)(drow[1] + k0 + g * 8);
        short8v b2 = *(const short8v*)(drow[2] + k0 + g * 8);
        short8v b3 = *(const short8v*)(drow[3] + k0 + g * 8);
#pragma unroll
        for (int cs = 0; cs < 8; cs++) {
            short8v a = *(const short8v*)(Wt + (size_t)(cs * 16 + r) * 320 + 128 + k0 + g * 8);
            acc[0][cs] = __builtin_amdgcn_mfma_f32_16x16x32_bf16(a, b0, acc[0][cs], 0, 0, 0);
            acc[1][cs] = __builtin_amdgcn_mfma_f32_16x16x32_bf16(a, b1, acc[1][cs], 0, 0, 0);
            acc[2][cs] = __builtin_amdgcn_mfma_f32_16x16x32_bf16(a, b2, acc[2][cs], 0, 0, 0);
            acc[3][cs] = __builtin_amdgcn_mfma_f32_16x16x32_bf16(a, b3, acc[3][cs], 0, 0, 0);
        }
    }
    // segment 3: k in [256,320) from e (fp32, convert on the fly)
#pragma unroll
    for (int ks = 0; ks < 2; ks++) {
        int k0 = ks * 32;
        short8v bv[4];
#pragma unroll
        for (int es = 0; es < 4; es++) {
            const float* ep = efeat + (size_t)eIdx[es] * 64 + k0 + g * 8;
            float4 f0 = *(const float4*)ep;
            float4 f1 = *(const float4*)(ep + 4);
            short8v b;
            b[0] = (short)f2bf(f0.x); b[1] = (short)f2bf(f0.y);
            b[2] = (short)f2bf(f0.z); b[3] = (short)f2bf(f0.w);
            b[4] = (short)f2bf(f1.x); b[5] = (short)f2bf(f1.y);
            b[6] = (short)f2bf(f1.z); b[7] = (short)f2bf(f1.w);
            bv[es] = b;
        }
#pragma unroll
        for (int cs = 0; cs < 8; cs++) {
            short8v a = *(const short8v*)(Wt + (size_t)(cs * 16 + r) * 320 + 256 + k0 + g * 8);
            acc[0][cs] = __builtin_amdgcn_mfma_f32_16x16x32_bf16(a, bv[0], acc[0][cs], 0, 0, 0);
            acc[1][cs] = __builtin_amdgcn_mfma_f32_16x16x32_bf16(a, bv[1], acc[1][cs], 0, 0, 0);
            acc[2][cs] = __builtin_amdgcn_mfma_f32_16x16x32_bf16(a, bv[2], acc[2][cs], 0, 0, 0);
            acc[3][cs] = __builtin_amdgcn_mfma_f32_16x16x32_bf16(a, bv[3], acc[3][cs], 0, 0, 0);
        }
    }

    // epilogue: lane packs 4 consecutive out-cols (reg dim) into one 8B store
#pragma unroll
    for (int cs = 0; cs < 8; cs++) {
        int c0 = cs * 16 + g * 4;
        float4 bi = *(const float4*)&bias[c0];
#pragma unroll
        for (int es = 0; es < 4; es++) {
            size_t edge = ebase + es * 16 + r;
            uint2 p;
            p.x = pack2(acc[es][cs][0] + bi.x, acc[es][cs][1] + bi.y);
            p.y = pack2(acc[es][cs][2] + bi.z, acc[es][cs][3] + bi.w);
            *(uint2*)&m[edge * 128 + c0] = p;
        }
    }
}

// ---------------- Aggregation: one wave per node, CSR walk ----------------
// writes sagg[N,1536] bf16 = [mean,max,min,std]x{1,amp,att} (post-GEMM A-matrix cols 128..1663)

__global__ __launch_bounds__(256) void agg_kernel(
    const u16* __restrict__ m, const int* __restrict__ rowstart,
    const int* __restrict__ eid, u16* __restrict__ sagg) {
    int w = blockIdx.x * 4 + (threadIdx.x >> 6);
    if (w >= NN) return;
    int lane = threadIdx.x & 63;
    int beg = rowstart[w], end = rowstart[w + 1];
    float s0 = 0.f, s1 = 0.f, q0 = 0.f, q1 = 0.f;
    float mx0 = -3.402823e38f, mx1 = -3.402823e38f;
    float mn0 = 3.402823e38f, mn1 = 3.402823e38f;
    for (int p = beg; p < end; p++) {
        int e2 = eid[p];
        u32 pk = *(const u32*)&m[(size_t)e2 * 128 + 2 * lane];
        float v0 = bf2f((u16)(pk & 0xffffu));
        float v1 = bf2f((u16)(pk >> 16));
        s0 += v0; s1 += v1;
        q0 += v0 * v0; q1 += v1 * v1;
        mx0 = fmaxf(mx0, v0); mx1 = fmaxf(mx1, v1);
        mn0 = fminf(mn0, v0); mn1 = fminf(mn1, v1);
    }
    int d = end - beg;
    size_t base = (size_t)w * 1536 + 2 * lane;
    if (d > 0) {
        float inv = 1.0f / (float)d;
        float me0 = s0 * inv, me1 = s1 * inv;
        float sd0 = sqrtf(fmaxf(q0 * inv - me0 * me0, 0.f) + EPSF);
        float sd1 = sqrtf(fmaxf(q1 * inv - me1 * me1, 0.f) + EPSF);
        float logd = logf((float)d + 1.0f);
        float sc[3];
        sc[0] = 1.0f;
        sc[1] = logd / AVGD;
        sc[2] = AVGD / fmaxf(logd, EPSF);
#pragma unroll
        for (int s = 0; s < 3; s++) {
            float k = sc[s];
            *(u32*)&sagg[base + s * 512 + 0]   = pack2(me0 * k, me1 * k);
            *(u32*)&sagg[base + s * 512 + 128] = pack2(mx0 * k, mx1 * k);
            *(u32*)&sagg[base + s * 512 + 256] = pack2(mn0 * k, mn1 * k);
            *(u32*)&sagg[base + s * 512 + 384] = pack2(sd0 * k, sd1 * k);
        }
    } else {
#pragma unroll
        for (int s = 0; s < 3; s++) {
            *(u32*)&sagg[base + s * 512 + 0]   = 0u;
            *(u32*)&sagg[base + s * 512 + 128] = 0u;
            *(u32*)&sagg[base + s * 512 + 256] = 0u;
            *(u32*)&sagg[base + s * 512 + 384] = 0u;
        }
    }
}

// ---------------- Post MFMA: ht[N,128] = cat(h_bf, sagg) @ postW + b (fp32 out) ----------------

__global__ __launch_bounds__(256, 2) void post_mfma(
    const u16* __restrict__ hb, const u16* __restrict__ sagg,
    const u16* __restrict__ Wt, const float* __restrict__ bias,
    float* __restrict__ ht) {
    int lane = threadIdx.x & 63;
    int wid = threadIdx.x >> 6;
    int r = lane & 15;
    int g = lane >> 4;
    size_t nbase = (size_t)blockIdx.x * 256 + wid * 64;

    int nd[4];
    const u16* hrow[4];
    const u16* srow[4];
#pragma unroll
    for (int es = 0; es < 4; es++) {
        int n2 = (int)nbase + es * 16 + r;
        nd[es] = n2;
        int nc = n2 < NN ? n2 : NN - 1;
        hrow[es] = hb + (size_t)nc * 128;
        srow[es] = sagg + (size_t)nc * 1536;
    }

    f32x4 acc[4][8];
#pragma unroll
    for (int es = 0; es < 4; es++)
#pragma unroll
        for (int cs = 0; cs < 8; cs++) acc[es][cs] = (f32x4)(0.f);

    // k in [0,128) from h_bf
#pragma unroll
    for (int ks = 0; ks < 4; ks++) {
        int k0 = ks * 32;
        short8v b0 = *(const short8v*)(hrow[0] + k0 + g * 8);
        short8v b1 = *(const short8v*)(hrow[1] + k0 + g * 8);
        short8v b2 = *(const short8v*)(hrow[2] + k0 + g * 8);
        short8v b3 = *(const short8v*)(hrow[3] + k0 + g * 8);
#pragma unroll
        for (int cs = 0; cs < 8; cs++) {
            short8v a = *(const short8v*)(Wt + (size_t)(cs * 16 + r) * 1664 + k0 + g * 8);
            acc[0][cs] = __builtin_amdgcn_mfma_f32_16x16x32_bf16(a, b0, acc[0][cs], 0, 0, 0);
            acc[1][cs] = __builtin_amdgcn_mfma_f32_16x16x32_bf16(a, b1, acc[1][cs], 0, 0, 0);
            acc[2][cs] = __builtin_amdgcn_mfma_f32_16x16x32_bf16(a, b2, acc[2][cs], 0, 0, 0);
            acc[3][cs] = __builtin_amdgcn_mfma_f32_16x16x32_bf16(a, b3, acc[3][cs], 0, 0, 0);
        }
    }
    // k in [128,1664) from sagg
#pragma unroll 4
    for (int ks = 0; ks < 48; ks++) {
        int k0 = ks * 32;
        short8v b0 = *(const short8v*)(srow[0] + k0 + g * 8);
        short8v b1 = *(const short8v*)(srow[1] + k0 + g * 8);
        short8v b2 = *(const short8v*)(srow[2] + k0 + g * 8);
        short8v b3 = *(const short8v*)(srow[3] + k0 + g * 8);
#pragma unroll
        for (int cs = 0; cs < 8; cs++) {
            short8v a = *(const short8v*)(Wt + (size_t)(cs * 16 + r) * 1664 + 128 + k0 + g * 8);
            acc[0][cs] = __builtin_amdgcn_mfma_f32_16x16x32_bf16(a, b0, acc[0][cs], 0, 0, 0);
            acc[1][cs] = __builtin_amdgcn_mfma_f32_16x16x32_bf16(a, b1, acc[1][cs], 0, 0, 0);
            acc[2][cs] = __builtin_amdgcn_mfma_f32_16x16x32_bf16(a, b2, acc[2][cs], 0, 0, 0);
            acc[3][cs] = __builtin_amdgcn_mfma_f32_16x16x32_bf16(a, b3, acc[3][cs], 0, 0, 0);
        }
    }

#pragma unroll
    for (int cs = 0; cs < 8; cs++) {
        int c0 = cs * 16 + g * 4;
        float4 bi = *(const float4*)&bias[c0];
#pragma unroll
        for (int es = 0; es < 4; es++) {
            if (nd[es] < NN) {
                float4 o;
                o.x = acc[es][cs][0] + bi.x;
                o.y = acc[es][cs][1] + bi.y;
                o.z = acc[es][cs][2] + bi.z;
                o.w = acc[es][cs][3] + bi.w;
                *(float4*)&ht[(size_t)nd[es] * 128 + c0] = o;
            }
        }
    }
}

// ---------------- Mix GEMM + leaky_relu + residual (fp32, small) ----------------

__global__ __launch_bounds__(256) void mix_kernel(
    const float* __restrict__ ht, const float* __restrict__ W,
    const float* __restrict__ bias, float* __restrict__ h) {
    __shared__ float As[16][68];
    __shared__ float Bs[16][132];
    int t = threadIdx.x;
    int row = t & 63;
    int kslot = t >> 6;
    int r0 = (t >> 4) << 2;
    int c0 = (t & 15) << 3;
    int gnode = blockIdx.x * 64 + row;
    int node = gnode < NN ? gnode : NN - 1;
    float acc[4][8];
#pragma unroll
    for (int i = 0; i < 4; i++)
#pragma unroll
        for (int j = 0; j < 8; j++) acc[i][j] = 0.f;

    for (int k0 = 0; k0 < 128; k0 += 16) {
#pragma unroll
        for (int i = 0; i < 4; i++) {
            int kk = kslot + 4 * i;
            As[kk][row] = ht[(size_t)node * 128 + k0 + kk];
        }
#pragma unroll
        for (int i = 0; i < 2; i++) {
            int f = t + i * 256;
            int kk = f >> 5;
            int c4 = (f & 31) << 2;
            *(float4*)&Bs[kk][c4] = *(const float4*)&W[(size_t)(k0 + kk) * 128 + c4];
        }
        __syncthreads();
#pragma unroll
        for (int kk = 0; kk < 16; kk++) {
            float4 a = *(const float4*)&As[kk][r0];
            float4 b0 = *(const float4*)&Bs[kk][c0];
            float4 b1 = *(const float4*)&Bs[kk][c0 + 4];
            float av[4] = {a.x, a.y, a.z, a.w};
            float bv[8] = {b0.x, b0.y, b0.z, b0.w, b1.x, b1.y, b1.z, b1.w};
#pragma unroll
            for (int i2 = 0; i2 < 4; i2++)
#pragma unroll
                for (int j = 0; j < 8; j++) acc[i2][j] += av[i2] * bv[j];
        }
        __syncthreads();
    }
#pragma unroll
    for (int i = 0; i < 4; i++) {
        int grow = blockIdx.x * 64 + r0 + i;
        if (grow < NN) {
#pragma unroll
            for (int j = 0; j < 8; j++) {
                float val = acc[i][j] + bias[c0 + j];
                val = val > 0.f ? val : 0.01f * val;
                size_t idx = (size_t)grow * 128 + c0 + j;
                h[idx] = h[idx] + val;
            }
        }
    }
}

// ---------------- launch ----------------

extern "C" void kernel_launch(void* const* d_in, const int* in_sizes, int n_in,
                              void* d_out, int out_size, void* d_ws, size_t ws_size,
                              hipStream_t stream) {
    (void)in_sizes; (void)n_in; (void)out_size; (void)ws_size;
    const float* h0    = (const float*)d_in[0];
    const float* efeat = (const float*)d_in[1];
    const int* src     = (const int*)d_in[2];
    const int* dst     = (const int*)d_in[3];
    const float* preW  = (const float*)d_in[4];
    const float* preB  = (const float*)d_in[5];
    const float* postW = (const float*)d_in[6];
    const float* postB = (const float*)d_in[7];
    const float* mixW  = (const float*)d_in[8];
    const float* mixB  = (const float*)d_in[9];
    float* hcur = (float*)d_out;

    char* ws = (char*)d_ws;
    size_t off = 0;
    auto alloc = [&](size_t bytes) {
        void* p = ws + off;
        off += (bytes + 255) & ~(size_t)255;
        return p;
    };
    u16* mbuf    = (u16*)alloc((size_t)EE * 128 * 2);    // 163.84 MB (aliased by ht fp32 25.6 MB)
    u16* sagg    = (u16*)alloc((size_t)NN * 1536 * 2);   // 153.60 MB
    u16* hb      = (u16*)alloc((size_t)NN * 128 * 2);    // 12.8 MB
    u16* preWt   = (u16*)alloc((size_t)128 * 320 * 2);
    u16* postWt  = (u16*)alloc((size_t)128 * 1664 * 2);
    int* eid     = (int*)alloc((size_t)EE * 4);
    int* deg     = (int*)alloc((size_t)NN * 4);
    int* rowstart= (int*)alloc((size_t)(NN + 1) * 4);
    int* cursor  = (int*)alloc((size_t)NN * 4);
    float* ht    = (float*)mbuf;  // alias: m dead once agg built

    hipMemsetAsync(deg, 0, (size_t)NN * 4, stream);
    hipMemsetAsync(cursor, 0, (size_t)NN * 4, stream);
    hipMemcpyAsync(hcur, h0, (size_t)NN * 128 * 4, hipMemcpyDeviceToDevice, stream);

    deg_kernel<<<(EE + 255) / 256, 256, 0, stream>>>(dst, deg);
    scan_kernel<<<1, 1024, 0, stream>>>(deg, rowstart);
    fill_kernel<<<(EE + 255) / 256, 256, 0, stream>>>(dst, rowstart, cursor, eid);

    for (int l = 0; l < 2; l++) {
        cvt_h_kernel<<<(NN * 128 / 4 + 255) / 256, 256, 0, stream>>>(hcur, hb);
        cvt_wt_kernel<<<(128 * 320 + 255) / 256, 256, 0, stream>>>(
            preW + (size_t)l * 320 * 128, preWt, 320);
        cvt_wt_kernel<<<(128 * 1664 + 255) / 256, 256, 0, stream>>>(
            postW + (size_t)l * 1664 * 128, postWt, 1664);

        pretrans_mfma<<<EE / 256, 256, 0, stream>>>(
            hb, efeat, src, dst, preWt, preB + (size_t)l * 128, mbuf);
        agg_kernel<<<(NN + 3) / 4, 256, 0, stream>>>(mbuf, rowstart, eid, sagg);
        post_mfma<<<(NN + 255) / 256, 256, 0, stream>>>(
            hb, sagg, postWt, postB + (size_t)l * 128, ht);
        mix_kernel<<<(NN + 63) / 64, 256, 0, stream>>>(
            ht, mixW + (size_t)l * 128 * 128, mixB + (size_t)l * 128, hcur);
    }
}

// Round 4
// 1259.977 us; speedup vs baseline: 2.3515x; 1.0912x over previous
//
#include <hip/hip_runtime.h>

#define NN 50000
#define EE 640000
#define KPRE 320
#define KPOST 1664
#define AVGD 3.5f
#define EPSF 1e-5f

typedef unsigned int u32;
typedef unsigned short u16;
typedef __attribute__((ext_vector_type(8))) short short8v;  // 8 bf16 in 4 VGPRs
typedef __attribute__((ext_vector_type(4))) float f32x4;

__device__ __forceinline__ u16 f2bf(float f) {
    u32 u = __float_as_uint(f);
    u32 r = (u + 0x7fffu + ((u >> 16) & 1u)) >> 16;
    return (u16)r;
}
__device__ __forceinline__ float bf2f(u16 b) {
    return __uint_as_float(((u32)b) << 16);
}
__device__ __forceinline__ u32 pack2(float a, float b) {
    return (u32)f2bf(a) | ((u32)f2bf(b) << 16);
}

// async global(per-lane) -> LDS(uniform base + lane*16), 16B per lane
__device__ __forceinline__ void gload_lds16(const u16* g, u16* l) {
    __builtin_amdgcn_global_load_lds(
        (const __attribute__((address_space(1))) void*)g,
        (__attribute__((address_space(3))) void*)l,
        16, 0, 0);
}

// ---------------- CSR construction ----------------

__global__ void deg_kernel(const int* __restrict__ dst, int* __restrict__ deg) {
    int i = blockIdx.x * blockDim.x + threadIdx.x;
    if (i < EE) atomicAdd(&deg[dst[i]], 1);
}

__global__ void scan_kernel(const int* __restrict__ deg, int* __restrict__ rowstart) {
    __shared__ int wsum[16];
    int lane = threadIdx.x & 63;
    int wid = threadIdx.x >> 6;
    int carry = 0;
    if (threadIdx.x == 0) rowstart[0] = 0;
    for (int base = 0; base < NN; base += 1024) {
        int i = base + threadIdx.x;
        int v = (i < NN) ? deg[i] : 0;
        int x = v;
#pragma unroll
        for (int off = 1; off < 64; off <<= 1) {
            int y = __shfl_up(x, off, 64);
            if (lane >= off) x += y;
        }
        if (lane == 63) wsum[wid] = x;
        __syncthreads();
        if (wid == 0 && lane < 16) {
            int w = wsum[lane];
#pragma unroll
            for (int off = 1; off < 16; off <<= 1) {
                int y = __shfl_up(w, off, 64);
                if (lane >= off) w += y;
            }
            wsum[lane] = w;
        }
        __syncthreads();
        int wofs = (wid > 0) ? wsum[wid - 1] : 0;
        int total = wsum[15];
        if (i < NN) rowstart[i + 1] = carry + wofs + x;
        carry += total;
        __syncthreads();
    }
}

__global__ void fill_kernel(const int* __restrict__ dst, const int* __restrict__ rowstart,
                            int* __restrict__ cursor, int* __restrict__ eid) {
    int i = blockIdx.x * blockDim.x + threadIdx.x;
    if (i < EE) {
        int d = dst[i];
        int pos = rowstart[d] + atomicAdd(&cursor[d], 1);
        eid[pos] = i;
    }
}

// psrc[p] = src[eid[p]], pdst[p] = dst[eid[p]]
__global__ void perm_idx_kernel(const int* __restrict__ eid,
                                const int* __restrict__ src, const int* __restrict__ dst,
                                int* __restrict__ psrc, int* __restrict__ pdst) {
    int p = blockIdx.x * blockDim.x + threadIdx.x;
    if (p < EE) {
        int e = eid[p];
        psrc[p] = src[e];
        pdst[p] = dst[e];
    }
}

// ---------------- converts ----------------

__global__ void cvt_h_kernel(const float* __restrict__ h, u16* __restrict__ hb) {
    int i = (blockIdx.x * blockDim.x + threadIdx.x) * 4;
    float4 v = *(const float4*)&h[i];
    uint2 p;
    p.x = pack2(v.x, v.y);
    p.y = pack2(v.z, v.w);
    *(uint2*)&hb[i] = p;
}

// W[K][128] fp32 -> Wt[128][K] bf16
__global__ void cvt_wt_kernel(const float* __restrict__ W, u16* __restrict__ Wt, int K) {
    int idx = blockIdx.x * blockDim.x + threadIdx.x;
    if (idx < 128 * K) {
        int c = idx / K;
        int k = idx - c * K;
        Wt[idx] = f2bf(W[(size_t)k * 128 + c]);
    }
}

// ---------------- Pretrans MFMA (LDS-staged, permuted edge order) ----------------
// block = 128 edges x 128 cols, 4 waves each 64 edges x 64 cols.
// K = 320 in 10 chunks of 32: chunks 0-3 from h[psrc], 4-7 from h[pdst],
// 8-9 from efeat[eid] (fp32 -> bf16 via registers).
// Gathered rows staged into LDS via global_load_lds (per-lane global src, linear LDS dst).
// m written at permuted position p (CSR order) -> agg reads sequentially.

__global__ __launch_bounds__(256, 3) void pretrans_mfma(
    const u16* __restrict__ hb, const float* __restrict__ efeat,
    const int* __restrict__ psrc, const int* __restrict__ pdst,
    const int* __restrict__ eid,
    const u16* __restrict__ Wt, const float* __restrict__ bias,
    u16* __restrict__ m) {
    __shared__ u16 lds[2][128][32];   // [buf][edge][kcol], 8KB per buf
    int t = threadIdx.x;
    int lane = t & 63;
    int wid = t >> 6;
    int r = lane & 15, g = lane >> 4;
    int wr = wid >> 1, wc = wid & 1;
    int blockbase = blockIdx.x * 128;

    // staging indices: wave wid stages edges wid*32 + j*16 + (lane>>2), quarter lane&3
    int se[2], de[2];
#pragma unroll
    for (int j = 0; j < 2; j++) {
        int e = blockbase + wid * 32 + j * 16 + (lane >> 2);
        se[j] = psrc[e];
        de[j] = pdst[e];
    }
    int q4 = lane & 3;
    int el = t >> 1, half = t & 1;          // for e-chunks: 2 threads per edge
    int eidv = eid[blockbase + el];

    f32x4 acc[4][4];
#pragma unroll
    for (int es = 0; es < 4; es++)
#pragma unroll
        for (int cs = 0; cs < 4; cs++) acc[es][cs] = (f32x4)(0.f);

    auto stage = [&](int c, int buf) {
        if (c < 8) {
            const int* idx = (c < 4) ? se : de;
            int kb = (c & 3) * 32;
#pragma unroll
            for (int j = 0; j < 2; j++) {
                const u16* gp = hb + (size_t)idx[j] * 128 + kb + q4 * 8;
                u16* lp = &lds[buf][wid * 32 + j * 16][0];
                gload_lds16(gp, lp);
            }
        } else {
            int kb = (c - 8) * 32;
            const float* ep = efeat + (size_t)eidv * 64 + kb + half * 16;
            short8v v0, v1;
#pragma unroll
            for (int q = 0; q < 2; q++) {
                float4 f = *(const float4*)(ep + q * 4);
                v0[q * 4 + 0] = (short)f2bf(f.x); v0[q * 4 + 1] = (short)f2bf(f.y);
                v0[q * 4 + 2] = (short)f2bf(f.z); v0[q * 4 + 3] = (short)f2bf(f.w);
            }
#pragma unroll
            for (int q = 0; q < 2; q++) {
                float4 f = *(const float4*)(ep + 8 + q * 4);
                v1[q * 4 + 0] = (short)f2bf(f.x); v1[q * 4 + 1] = (short)f2bf(f.y);
                v1[q * 4 + 2] = (short)f2bf(f.z); v1[q * 4 + 3] = (short)f2bf(f.w);
            }
            *(short8v*)&lds[buf][el][half * 16] = v0;
            *(short8v*)&lds[buf][el][half * 16 + 8] = v1;
        }
    };

    stage(0, 0);
#pragma unroll
    for (int c = 0; c < 10; c++) {
        __syncthreads();                    // buf[c&1] staged; prior reads of other buf done
        if (c < 9) stage(c + 1, (c + 1) & 1);
        int kg = c * 32;
        short8v bfr[4];
#pragma unroll
        for (int es = 0; es < 4; es++)
            bfr[es] = *(const short8v*)&lds[c & 1][wr * 64 + es * 16 + r][g * 8];
#pragma unroll
        for (int cs = 0; cs < 4; cs++) {
            short8v a = *(const short8v*)(Wt + (size_t)(wc * 64 + cs * 16 + r) * KPRE + kg + g * 8);
#pragma unroll
            for (int es = 0; es < 4; es++)
                acc[es][cs] = __builtin_amdgcn_mfma_f32_16x16x32_bf16(a, bfr[es], acc[es][cs], 0, 0, 0);
        }
    }

    // D layout: edge = es*16 + r, col = cs*16 + g*4 + reg. Sequential (permuted) m write.
#pragma unroll
    for (int cs = 0; cs < 4; cs++) {
        int c0 = wc * 64 + cs * 16 + g * 4;
        float4 bi = *(const float4*)&bias[c0];
#pragma unroll
        for (int es = 0; es < 4; es++) {
            size_t gedge = (size_t)blockbase + wr * 64 + es * 16 + r;
            uint2 p;
            p.x = pack2(acc[es][cs][0] + bi.x, acc[es][cs][1] + bi.y);
            p.y = pack2(acc[es][cs][2] + bi.z, acc[es][cs][3] + bi.w);
            *(uint2*)&m[gedge * 128 + c0] = p;
        }
    }
}

// ---------------- Aggregation: one wave per node, SEQUENTIAL m rows ----------------
// writes sagg[N,1536] bf16 = [mean,max,min,std] x {1, amp, att}

__global__ __launch_bounds__(256) void agg_kernel(
    const u16* __restrict__ m, const int* __restrict__ rowstart,
    u16* __restrict__ sagg) {
    int w = blockIdx.x * 4 + (threadIdx.x >> 6);
    if (w >= NN) return;
    int lane = threadIdx.x & 63;
    int beg = rowstart[w], end = rowstart[w + 1];
    float s0 = 0.f, s1 = 0.f, q0 = 0.f, q1 = 0.f;
    float mx0 = -3.402823e38f, mx1 = -3.402823e38f;
    float mn0 = 3.402823e38f, mn1 = 3.402823e38f;
    for (int p = beg; p < end; p++) {
        u32 pk = *(const u32*)&m[(size_t)p * 128 + 2 * lane];
        float v0 = bf2f((u16)(pk & 0xffffu));
        float v1 = bf2f((u16)(pk >> 16));
        s0 += v0; s1 += v1;
        q0 += v0 * v0; q1 += v1 * v1;
        mx0 = fmaxf(mx0, v0); mx1 = fmaxf(mx1, v1);
        mn0 = fminf(mn0, v0); mn1 = fminf(mn1, v1);
    }
    int d = end - beg;
    size_t base = (size_t)w * 1536 + 2 * lane;
    if (d > 0) {
        float inv = 1.0f / (float)d;
        float me0 = s0 * inv, me1 = s1 * inv;
        float sd0 = sqrtf(fmaxf(q0 * inv - me0 * me0, 0.f) + EPSF);
        float sd1 = sqrtf(fmaxf(q1 * inv - me1 * me1, 0.f) + EPSF);
        float logd = logf((float)d + 1.0f);
        float sc[3];
        sc[0] = 1.0f;
        sc[1] = logd / AVGD;
        sc[2] = AVGD / fmaxf(logd, EPSF);
#pragma unroll
        for (int s = 0; s < 3; s++) {
            float k = sc[s];
            *(u32*)&sagg[base + s * 512 + 0]   = pack2(me0 * k, me1 * k);
            *(u32*)&sagg[base + s * 512 + 128] = pack2(mx0 * k, mx1 * k);
            *(u32*)&sagg[base + s * 512 + 256] = pack2(mn0 * k, mn1 * k);
            *(u32*)&sagg[base + s * 512 + 384] = pack2(sd0 * k, sd1 * k);
        }
    } else {
#pragma unroll
        for (int s = 0; s < 3; s++) {
            *(u32*)&sagg[base + s * 512 + 0]   = 0u;
            *(u32*)&sagg[base + s * 512 + 128] = 0u;
            *(u32*)&sagg[base + s * 512 + 256] = 0u;
            *(u32*)&sagg[base + s * 512 + 384] = 0u;
        }
    }
}

// ---------------- Post MFMA: htb[N,128] bf16 = cat(hb, sagg) @ postW + b ----------------
// wave = 32 nodes x 128 cols (grid 391 blocks)

__global__ __launch_bounds__(256, 2) void post_mfma(
    const u16* __restrict__ hb, const u16* __restrict__ sagg,
    const u16* __restrict__ Wt, const float* __restrict__ bias,
    u16* __restrict__ htb) {
    int lane = threadIdx.x & 63;
    int wid = threadIdx.x >> 6;
    int r = lane & 15;
    int g = lane >> 4;
    int nbase = blockIdx.x * 128 + wid * 32;

    int nd[2];
    const u16* hrow[2];
    const u16* srow[2];
#pragma unroll
    for (int es = 0; es < 2; es++) {
        int n2 = nbase + es * 16 + r;
        nd[es] = n2;
        int nc = n2 < NN ? n2 : NN - 1;
        hrow[es] = hb + (size_t)nc * 128;
        srow[es] = sagg + (size_t)nc * 1536;
    }

    f32x4 acc[2][8];
#pragma unroll
    for (int es = 0; es < 2; es++)
#pragma unroll
        for (int cs = 0; cs < 8; cs++) acc[es][cs] = (f32x4)(0.f);

    // k in [0,128) from hb
#pragma unroll
    for (int ks = 0; ks < 4; ks++) {
        int k0 = ks * 32;
        short8v b0 = *(const short8v*)(hrow[0] + k0 + g * 8);
        short8v b1 = *(const short8v*)(hrow[1] + k0 + g * 8);
#pragma unroll
        for (int cs = 0; cs < 8; cs++) {
            short8v a = *(const short8v*)(Wt + (size_t)(cs * 16 + r) * KPOST + k0 + g * 8);
            acc[0][cs] = __builtin_amdgcn_mfma_f32_16x16x32_bf16(a, b0, acc[0][cs], 0, 0, 0);
            acc[1][cs] = __builtin_amdgcn_mfma_f32_16x16x32_bf16(a, b1, acc[1][cs], 0, 0, 0);
        }
    }
    // k in [128,1664) from sagg
#pragma unroll 4
    for (int ks = 0; ks < 48; ks++) {
        int k0 = ks * 32;
        short8v b0 = *(const short8v*)(srow[0] + k0 + g * 8);
        short8v b1 = *(const short8v*)(srow[1] + k0 + g * 8);
#pragma unroll
        for (int cs = 0; cs < 8; cs++) {
            short8v a = *(const short8v*)(Wt + (size_t)(cs * 16 + r) * KPOST + 128 + k0 + g * 8);
            acc[0][cs] = __builtin_amdgcn_mfma_f32_16x16x32_bf16(a, b0, acc[0][cs], 0, 0, 0);
            acc[1][cs] = __builtin_amdgcn_mfma_f32_16x16x32_bf16(a, b1, acc[1][cs], 0, 0, 0);
        }
    }

#pragma unroll
    for (int cs = 0; cs < 8; cs++) {
        int c0 = cs * 16 + g * 4;
        float4 bi = *(const float4*)&bias[c0];
#pragma unroll
        for (int es = 0; es < 2; es++) {
            if (nd[es] < NN) {
                uint2 p;
                p.x = pack2(acc[es][cs][0] + bi.x, acc[es][cs][1] + bi.y);
                p.y = pack2(acc[es][cs][2] + bi.z, acc[es][cs][3] + bi.w);
                *(uint2*)&htb[(size_t)nd[es] * 128 + c0] = p;
            }
        }
    }
}

// ---------------- Mix MFMA + leaky_relu + residual; writes h fp32 AND hb bf16 ----------------
// wave = 16 nodes x 128 cols (grid 782 blocks)

__global__ __launch_bounds__(256, 2) void mix_mfma(
    const u16* __restrict__ htb, const u16* __restrict__ Wt,
    const float* __restrict__ bias, float* __restrict__ h, u16* __restrict__ hb) {
    int lane = threadIdx.x & 63;
    int wid = threadIdx.x >> 6;
    int r = lane & 15;
    int g = lane >> 4;
    int node = blockIdx.x * 64 + wid * 16 + r;
    int nc = node < NN ? node : NN - 1;
    const u16* brow = htb + (size_t)nc * 128;

    f32x4 acc[8];
#pragma unroll
    for (int cs = 0; cs < 8; cs++) acc[cs] = (f32x4)(0.f);

#pragma unroll
    for (int ks = 0; ks < 4; ks++) {
        int k0 = ks * 32;
        short8v b = *(const short8v*)(brow + k0 + g * 8);
#pragma unroll
        for (int cs = 0; cs < 8; cs++) {
            short8v a = *(const short8v*)(Wt + (size_t)(cs * 16 + r) * 128 + k0 + g * 8);
            acc[cs] = __builtin_amdgcn_mfma_f32_16x16x32_bf16(a, b, acc[cs], 0, 0, 0);
        }
    }

    if (node < NN) {
#pragma unroll
        for (int cs = 0; cs < 8; cs++) {
            int c0 = cs * 16 + g * 4;
            float4 bi = *(const float4*)&bias[c0];
            float4 v;
            v.x = acc[cs][0] + bi.x; v.y = acc[cs][1] + bi.y;
            v.z = acc[cs][2] + bi.z; v.w = acc[cs][3] + bi.w;
            v.x = v.x > 0.f ? v.x : 0.01f * v.x;
            v.y = v.y > 0.f ? v.y : 0.01f * v.y;
            v.z = v.z > 0.f ? v.z : 0.01f * v.z;
            v.w = v.w > 0.f ? v.w : 0.01f * v.w;
            size_t idx = (size_t)node * 128 + c0;
            float4 old = *(const float4*)&h[idx];
            float4 nw;
            nw.x = old.x + v.x; nw.y = old.y + v.y;
            nw.z = old.z + v.z; nw.w = old.w + v.w;
            *(float4*)&h[idx] = nw;
            uint2 pb;
            pb.x = pack2(nw.x, nw.y);
            pb.y = pack2(nw.z, nw.w);
            *(uint2*)&hb[idx] = pb;
        }
    }
}

// ---------------- launch ----------------

extern "C" void kernel_launch(void* const* d_in, const int* in_sizes, int n_in,
                              void* d_out, int out_size, void* d_ws, size_t ws_size,
                              hipStream_t stream) {
    (void)in_sizes; (void)n_in; (void)out_size; (void)ws_size;
    const float* h0    = (const float*)d_in[0];
    const float* efeat = (const float*)d_in[1];
    const int* src     = (const int*)d_in[2];
    const int* dst     = (const int*)d_in[3];
    const float* preW  = (const float*)d_in[4];
    const float* preB  = (const float*)d_in[5];
    const float* postW = (const float*)d_in[6];
    const float* postB = (const float*)d_in[7];
    const float* mixW  = (const float*)d_in[8];
    const float* mixB  = (const float*)d_in[9];
    float* hcur = (float*)d_out;

    char* ws = (char*)d_ws;
    size_t off = 0;
    auto alloc = [&](size_t bytes) {
        void* p = ws + off;
        off += (bytes + 255) & ~(size_t)255;
        return p;
    };
    u16* mbuf    = (u16*)alloc((size_t)EE * 128 * 2);    // 163.84 MB (aliased by htb 12.8 MB)
    u16* sagg    = (u16*)alloc((size_t)NN * 1536 * 2);   // 153.60 MB
    u16* hb      = (u16*)alloc((size_t)NN * 128 * 2);    // 12.8 MB
    u16* preWt   = (u16*)alloc((size_t)128 * KPRE * 2);
    u16* postWt  = (u16*)alloc((size_t)128 * KPOST * 2);
    u16* mixWt   = (u16*)alloc((size_t)128 * 128 * 2);
    int* eid     = (int*)alloc((size_t)EE * 4);
    int* psrc    = (int*)alloc((size_t)EE * 4);
    int* pdst    = (int*)alloc((size_t)EE * 4);
    int* deg     = (int*)alloc((size_t)NN * 4);
    int* rowstart= (int*)alloc((size_t)(NN + 1) * 4);
    int* cursor  = (int*)alloc((size_t)NN * 4);
    u16* htb     = (u16*)mbuf;   // alias: m dead once agg built; htb dead before next pretrans

    hipMemsetAsync(deg, 0, (size_t)NN * 4, stream);
    hipMemsetAsync(cursor, 0, (size_t)NN * 4, stream);
    hipMemcpyAsync(hcur, h0, (size_t)NN * 128 * 4, hipMemcpyDeviceToDevice, stream);

    deg_kernel<<<(EE + 255) / 256, 256, 0, stream>>>(dst, deg);
    scan_kernel<<<1, 1024, 0, stream>>>(deg, rowstart);
    fill_kernel<<<(EE + 255) / 256, 256, 0, stream>>>(dst, rowstart, cursor, eid);
    perm_idx_kernel<<<(EE + 255) / 256, 256, 0, stream>>>(eid, src, dst, psrc, pdst);
    cvt_h_kernel<<<(NN * 128 / 4 + 255) / 256, 256, 0, stream>>>(hcur, hb);

    for (int l = 0; l < 2; l++) {
        cvt_wt_kernel<<<(128 * KPRE + 255) / 256, 256, 0, stream>>>(
            preW + (size_t)l * KPRE * 128, preWt, KPRE);
        cvt_wt_kernel<<<(128 * KPOST + 255) / 256, 256, 0, stream>>>(
            postW + (size_t)l * KPOST * 128, postWt, KPOST);
        cvt_wt_kernel<<<(128 * 128 + 255) / 256, 256, 0, stream>>>(
            mixW + (size_t)l * 128 * 128, mixWt, 128);

        pretrans_mfma<<<EE / 128, 256, 0, stream>>>(
            hb, efeat, psrc, pdst, eid, preWt, preB + (size_t)l * 128, mbuf);
        agg_kernel<<<(NN + 3) / 4, 256, 0, stream>>>(mbuf, rowstart, sagg);
        post_mfma<<<(NN + 127) / 128, 256, 0, stream>>>(
            hb, sagg, postWt, postB + (size_t)l * 128, htb);
        mix_mfma<<<(NN + 63) / 64, 256, 0, stream>>>(
            htb, mixWt, mixB + (size_t)l * 128, hcur, hb);
    }
}